// Round 2
// baseline (1394.086 us; speedup 1.0000x reference)
//
#include <hip/hip_runtime.h>
#include <cstdint>
#include <cstddef>

// CrossAttention1d: N=4, C=512, S=2048, CTX=512, S2=2048, H=8
// Pipeline: LN stats -> normalize+transpose(bf16) -> Q/KV GEMMs (MFMA bf16)
//           -> flash attention (online softmax, MFMA) -> out GEMM + residual.
// Launcher adapts workspace layout to ws_size (Round 0 faulted: 288 MB plan
// likely exceeded the harness workspace; paths B/C reuse per-batch buffers).

#define NB 4
#define CC 512
#define SS 2048
#define HH 8
#define QK_SCALE 0.044194173824159216f  // 512^-0.5 (== C^-0.25 applied to q and k)

typedef float  floatx4 __attribute__((ext_vector_type(4)));
typedef __bf16 bf16x8  __attribute__((ext_vector_type(8)));
typedef __bf16 bf16x4  __attribute__((ext_vector_type(4)));

__device__ __forceinline__ void async16(const void* g, void* l) {
  __builtin_amdgcn_global_load_lds((const __attribute__((address_space(1))) void*)g,
                                   (__attribute__((address_space(3))) void*)l, 16, 0, 0);
}

// ---------------- LayerNorm stats ----------------
__global__ void ln_partial(const float* __restrict__ x, float* __restrict__ part) {
  const int n = blockIdx.x >> 7, cidx = blockIdx.x & 127;
  const float* p = x + (size_t)n * (CC * SS) + (size_t)cidx * 8192;
  float s = 0.f, q = 0.f;
  for (int j = 0; j < 8; ++j) {
    floatx4 v = *(const floatx4*)&p[(j * 256 + threadIdx.x) * 4];
    for (int e = 0; e < 4; ++e) { s += v[e]; q += v[e] * v[e]; }
  }
  for (int off = 32; off >= 1; off >>= 1) {
    s += __shfl_down(s, off, 64);
    q += __shfl_down(q, off, 64);
  }
  __shared__ float shS[4], shQ[4];
  const int wave = threadIdx.x >> 6, lane = threadIdx.x & 63;
  if (lane == 0) { shS[wave] = s; shQ[wave] = q; }
  __syncthreads();
  if (threadIdx.x == 0) {
    float S = shS[0] + shS[1] + shS[2] + shS[3];
    float Q = shQ[0] + shQ[1] + shQ[2] + shQ[3];
    part[blockIdx.x * 2] = S;
    part[blockIdx.x * 2 + 1] = Q;
  }
}

__global__ void ln_final(const float* __restrict__ part, float* __restrict__ muA,
                         float* __restrict__ rsA) {
  const int n = blockIdx.x, tid = threadIdx.x;
  float s = part[(n * 128 + tid) * 2];
  float q = part[(n * 128 + tid) * 2 + 1];
  for (int off = 32; off >= 1; off >>= 1) {
    s += __shfl_down(s, off, 64);
    q += __shfl_down(q, off, 64);
  }
  __shared__ float shS[2], shQ[2];
  const int wave = tid >> 6, lane = tid & 63;
  if (lane == 0) { shS[wave] = s; shQ[wave] = q; }
  __syncthreads();
  if (tid == 0) {
    float S = shS[0] + shS[1], Q = shQ[0] + shQ[1];
    const float inv = 1.f / (float)(CC * SS);
    float m = S * inv;
    float v = Q * inv - m * m;
    muA[n] = m;
    rsA[n] = rsqrtf(v + 1e-5f);
  }
}

// ---------------- weight cast fp32 -> bf16 ----------------
__global__ void cast_w(const float* __restrict__ w, __bf16* __restrict__ o, int n4) {
  int idx = blockIdx.x * 256 + threadIdx.x;
  if (idx >= n4) return;
  floatx4 v = ((const floatx4*)w)[idx];
  bf16x4 pk;
  for (int e = 0; e < 4; ++e) pk[e] = (__bf16)v[e];
  ((bf16x4*)o)[idx] = pk;
}

// ---------------- normalize (optional) + transpose bf16 ----------------
// in: (R=512, cols=2048) per batch ; out: (2048, 512) per batch
__global__ void transpose_norm(const float* __restrict__ in, __bf16* __restrict__ out,
                               const float* __restrict__ mu, const float* __restrict__ rstd,
                               const float* __restrict__ gamma, const float* __restrict__ beta) {
  __shared__ float t[32][33];
  const int n = blockIdx.z;
  const int c0 = blockIdx.y * 32, s0 = blockIdx.x * 32;
  const float muv = mu ? mu[n] : 0.f;
  const float rs = rstd ? rstd[n] : 1.f;
  const float* inp = in + (size_t)n * CC * SS;
  for (int i = 0; i < 4; ++i) {
    int c = c0 + threadIdx.y + i * 8;
    float x = inp[(size_t)c * SS + s0 + threadIdx.x];
    if (gamma) x = (x - muv) * rs * gamma[c] + beta[c];
    t[threadIdx.y + i * 8][threadIdx.x] = x;
  }
  __syncthreads();
  __bf16* op = out + (size_t)n * SS * CC;
  for (int i = 0; i < 4; ++i) {
    int s = s0 + threadIdx.y + i * 8;
    op[(size_t)s * CC + c0 + threadIdx.x] = (__bf16)t[threadIdx.x][threadIdx.y + i * 8];
  }
}

// ---------------- shared GEMM mainloop: C(128x128) = A(MxK,row) * Bt(NxK,row)^T ----------------
__device__ __forceinline__ void gemm_tile_128(const __bf16* __restrict__ A,
                                              const __bf16* __restrict__ Bt, int K,
                                              int m0, int n0, __bf16* ldsA, __bf16* ldsB,
                                              floatx4 acc[4][4]) {
  const int tid = threadIdx.x;
  const int wave = tid >> 6, lane = tid & 63;
  const int colv = lane & 15, g = lane >> 4;
  const int wm = wave & 1, wn = wave >> 1;
  const int lrow = lane >> 3, lch = lane & 7;

#pragma unroll
  for (int mt = 0; mt < 4; ++mt)
#pragma unroll
    for (int nt = 0; nt < 4; ++nt) acc[mt][nt] = (floatx4)0.f;

  for (int k0 = 0; k0 < K; k0 += 64) {
    __syncthreads();
#pragma unroll
    for (int j = 0; j < 4; ++j) {
      int r = wave * 32 + j * 8 + lrow;
      int ch = lch ^ (r & 7);
      async16(A + (size_t)(m0 + r) * K + k0 + ch * 8, &ldsA[(wave * 32 + j * 8) * 64]);
      async16(Bt + (size_t)(n0 + r) * K + k0 + ch * 8, &ldsB[(wave * 32 + j * 8) * 64]);
    }
    __syncthreads();
#pragma unroll
    for (int c = 0; c < 2; ++c) {
      bf16x8 af[4], bf[4];
#pragma unroll
      for (int t = 0; t < 4; ++t) {
        int r = wm * 64 + t * 16 + colv;
        af[t] = *(const bf16x8*)&ldsA[r * 64 + (((c * 4 + g) ^ (r & 7)) << 3)];
        int rb = wn * 64 + t * 16 + colv;
        bf[t] = *(const bf16x8*)&ldsB[rb * 64 + (((c * 4 + g) ^ (rb & 7)) << 3)];
      }
#pragma unroll
      for (int mt = 0; mt < 4; ++mt)
#pragma unroll
        for (int nt = 0; nt < 4; ++nt)
          acc[mt][nt] = __builtin_amdgcn_mfma_f32_16x16x32_bf16(af[mt], bf[nt], acc[mt][nt], 0, 0, 0);
    }
  }
}

// ---------------- GEMM 1: qT[n](2048x4096) = (Wq*xn)^T + bq ----------------
__global__ void __launch_bounds__(256) gemm_q(const __bf16* __restrict__ Wq,
                                              const __bf16* __restrict__ xnT,
                                              const float* __restrict__ bq,
                                              __bf16* __restrict__ qT) {
  __shared__ __bf16 lA[128 * 64], lB[128 * 64];
  const int n = blockIdx.z;
  const int m0 = blockIdx.x * 128, n0 = blockIdx.y * 128;
  floatx4 acc[4][4];
  gemm_tile_128(Wq, xnT + (size_t)n * SS * CC, CC, m0, n0, lA, lB, acc);
  const int lane = threadIdx.x & 63, wave = threadIdx.x >> 6;
  const int colv = lane & 15, g = lane >> 4;
  const int wm = wave & 1, wn = wave >> 1;
  __bf16* qn = qT + (size_t)n * SS * 4096;
#pragma unroll
  for (int mt = 0; mt < 4; ++mt) {
    int o = m0 + wm * 64 + mt * 16 + g * 4;
    floatx4 bias = *(const floatx4*)&bq[o];
#pragma unroll
    for (int nt = 0; nt < 4; ++nt) {
      int s = n0 + wn * 64 + nt * 16 + colv;
      bf16x4 pk;
#pragma unroll
      for (int i = 0; i < 4; ++i) pk[i] = (__bf16)(acc[mt][nt][i] + bias[i]);
      *(bf16x4*)&qn[(size_t)s * 4096 + o] = pk;
    }
  }
}

// ---------------- GEMM 2: kv; K-half -> kT[n](2048x4096), V-half -> v[n](4096x2048) ----------------
__global__ void __launch_bounds__(256) gemm_kv(const __bf16* __restrict__ Wkv,
                                               const __bf16* __restrict__ ctxT,
                                               const float* __restrict__ bkv,
                                               __bf16* __restrict__ kT,
                                               __bf16* __restrict__ vv) {
  __shared__ __bf16 lA[128 * 64], lB[128 * 64];
  const int n = blockIdx.z;
  const int m0 = blockIdx.x * 128, n0 = blockIdx.y * 128;
  floatx4 acc[4][4];
  gemm_tile_128(Wkv, ctxT + (size_t)n * SS * CC, CC, m0, n0, lA, lB, acc);
  const int lane = threadIdx.x & 63, wave = threadIdx.x >> 6;
  const int colv = lane & 15, g = lane >> 4;
  const int wm = wave & 1, wn = wave >> 1;
  if (m0 < 4096) {
    __bf16* kn = kT + (size_t)n * SS * 4096;
#pragma unroll
    for (int mt = 0; mt < 4; ++mt) {
      int o = m0 + wm * 64 + mt * 16 + g * 4;
      floatx4 bias = *(const floatx4*)&bkv[o];
#pragma unroll
      for (int nt = 0; nt < 4; ++nt) {
        int s = n0 + wn * 64 + nt * 16 + colv;
        bf16x4 pk;
#pragma unroll
        for (int i = 0; i < 4; ++i) pk[i] = (__bf16)(acc[mt][nt][i] + bias[i]);
        *(bf16x4*)&kn[(size_t)s * 4096 + o] = pk;
      }
    }
  } else {
    __bf16* vn = vv + (size_t)n * 4096 * SS;
#pragma unroll
    for (int mt = 0; mt < 4; ++mt) {
      int o = m0 + wm * 64 + mt * 16 + g * 4;
      floatx4 bias = *(const floatx4*)&bkv[o];
#pragma unroll
      for (int nt = 0; nt < 4; ++nt) {
        int s = n0 + wn * 64 + nt * 16 + colv;
#pragma unroll
        for (int i = 0; i < 4; ++i)
          vn[(size_t)(o + i - 4096) * SS + s] = (__bf16)(acc[mt][nt][i] + bias[i]);
      }
    }
  }
}

// ---------------- flash attention ----------------
// grid (S/64, H, nb); block 256 = 4 waves; wave handles 16 queries, full D=512.
__global__ void __launch_bounds__(256) flash_attn(const __bf16* __restrict__ qT,
                                                  const __bf16* __restrict__ kT,
                                                  const __bf16* __restrict__ vv,
                                                  __bf16* __restrict__ yT) {
  const int n = blockIdx.z, h = blockIdx.y, qt = blockIdx.x;
  const int tid = threadIdx.x;
  const int wave = tid >> 6, lane = tid & 63;
  const int colv = lane & 15, g = lane >> 4;

  const __bf16* qTn = qT + (size_t)n * SS * 4096;
  const __bf16* kTn = kT + (size_t)n * SS * 4096;
  const __bf16* vn  = vv + (size_t)n * 4096 * SS;
  __bf16* yTn = yT + (size_t)n * SS * 4096;

  const int qrow0 = qt * 64 + wave * 16;

  __shared__ __bf16 kbuf[32 * 512];  // row = key (1KB, 64 chunks, xor-swizzled by key&7)
  __shared__ __bf16 vbuf[512 * 32];  // row = d   (64B,  4 chunks, xor-swizzled by d&3)

  // Q fragments held in registers: 16 kchunks x 16B
  bf16x8 qf[16];
  {
    const __bf16* qp = qTn + (size_t)(qrow0 + colv) * 4096 + h * 512 + g * 8;
#pragma unroll
    for (int kc = 0; kc < 16; ++kc) qf[kc] = *(const bf16x8*)(qp + kc * 32);
  }

  floatx4 Oacc[32];
#pragma unroll
  for (int dt = 0; dt < 32; ++dt) Oacc[dt] = (floatx4)0.f;
  float mrun[4] = {-1e30f, -1e30f, -1e30f, -1e30f};
  float lrun[4] = {0.f, 0.f, 0.f, 0.f};

  // per-wave P staging aliased into kbuf (written after barrier (c), read before barrier (a))
  __bf16* pb = kbuf + wave * (16 * 88);

  for (int kt = 0; kt < 64; ++kt) {
    const int key0 = kt * 32;
    __syncthreads();  // (a) prior tile's kbuf/vbuf reads done
#pragma unroll
    for (int j = 0; j < 8; ++j) {
      int row = wave * 8 + j;
      const __bf16* src = kTn + (size_t)(key0 + row) * 4096 + h * 512 + ((lane ^ (row & 7)) << 3);
      async16(src, &kbuf[row * 512]);
    }
#pragma unroll
    for (int j = 0; j < 8; ++j) {
      int i = wave * 8 + j;
      int row = i * 16 + (lane >> 2);
      int ch = (lane & 3) ^ (row & 3);
      const __bf16* src = vn + (size_t)(h * 512 + row) * SS + key0 + ch * 8;
      async16(src, &vbuf[i * 16 * 32]);
    }
    __syncthreads();  // (b) staging complete

    floatx4 sc[2];
    sc[0] = (floatx4)0.f;
    sc[1] = (floatx4)0.f;
#pragma unroll
    for (int ct = 0; ct < 2; ++ct) {
      int key = ct * 16 + colv;
      const __bf16* kb = &kbuf[key * 512];
      int sw = key & 7;
#pragma unroll
      for (int kc = 0; kc < 16; ++kc) {
        bf16x8 bfr = *(const bf16x8*)(kb + (((kc * 4 + g) ^ sw) << 3));
        sc[ct] = __builtin_amdgcn_mfma_f32_16x16x32_bf16(qf[kc], bfr, sc[ct], 0, 0, 0);
      }
    }
    __syncthreads();  // (c) all kbuf score reads done -> P region writable

    float p[2][4];
    float alpha[4];
#pragma unroll
    for (int i = 0; i < 4; ++i) {
      float mx = fmaxf(sc[0][i], sc[1][i]);
#pragma unroll
      for (int off = 8; off >= 1; off >>= 1) mx = fmaxf(mx, __shfl_xor(mx, off, 64));
      float mnew = fmaxf(mrun[i], mx * QK_SCALE);
      alpha[i] = __expf(mrun[i] - mnew);
      float rs = 0.f;
#pragma unroll
      for (int ct = 0; ct < 2; ++ct) {
        float pvv = __expf(sc[ct][i] * QK_SCALE - mnew);
        p[ct][i] = pvv;
        rs += pvv;
      }
#pragma unroll
      for (int off = 8; off >= 1; off >>= 1) rs += __shfl_xor(rs, off, 64);
      lrun[i] = lrun[i] * alpha[i] + rs;
      mrun[i] = mnew;
    }
#pragma unroll
    for (int ct = 0; ct < 2; ++ct)
#pragma unroll
      for (int i = 0; i < 4; ++i)
        pb[(g * 4 + i) * 88 + ct * 16 + colv] = (__bf16)p[ct][i];
#pragma unroll
    for (int dt = 0; dt < 32; ++dt) {
      floatx4 o = Oacc[dt];
#pragma unroll
      for (int i = 0; i < 4; ++i) o[i] *= alpha[i];
      Oacc[dt] = o;
    }
    bf16x8 pa = *(const bf16x8*)&pb[colv * 88 + g * 8];
#pragma unroll
    for (int dt = 0; dt < 32; ++dt) {
      int drow = dt * 16 + colv;
      bf16x8 vb = *(const bf16x8*)&vbuf[drow * 32 + ((g ^ (drow & 3)) << 3)];
      Oacc[dt] = __builtin_amdgcn_mfma_f32_16x16x32_bf16(pa, vb, Oacc[dt], 0, 0, 0);
    }
  }

  float inv[4];
#pragma unroll
  for (int i = 0; i < 4; ++i) inv[i] = 1.f / lrun[i];
#pragma unroll
  for (int dt = 0; dt < 32; ++dt)
#pragma unroll
    for (int i = 0; i < 4; ++i) {
      size_t idx = (size_t)(qrow0 + g * 4 + i) * 4096 + h * 512 + dt * 16 + colv;
      yTn[idx] = (__bf16)(Oacc[dt][i] * inv[i]);
    }
}

// ---------------- GEMM 3: out[n][c][s] = input + Wo*y + bo ----------------
// A = yT (M=2048=s, K=4096), Bt = Wo (N=512=c, K=4096)
__global__ void __launch_bounds__(256) gemm_out(const __bf16* __restrict__ yT,
                                                const __bf16* __restrict__ Wo,
                                                const float* __restrict__ bo,
                                                const float* __restrict__ xin,
                                                float* __restrict__ out) {
  __shared__ __bf16 lA[128 * 64], lB[128 * 64];
  const int n = blockIdx.z;
  const int m0 = blockIdx.x * 128, n0 = blockIdx.y * 128;
  floatx4 acc[4][4];
  gemm_tile_128(yT + (size_t)n * SS * 4096, Wo, 4096, m0, n0, lA, lB, acc);
  const int lane = threadIdx.x & 63, wave = threadIdx.x >> 6;
  const int colv = lane & 15, g = lane >> 4;
  const int wm = wave & 1, wn = wave >> 1;
#pragma unroll
  for (int mt = 0; mt < 4; ++mt) {
    int srow = m0 + wm * 64 + mt * 16 + g * 4;
#pragma unroll
    for (int nt = 0; nt < 4; ++nt) {
      int ccol = n0 + wn * 64 + nt * 16 + colv;
      float bov = bo[ccol];
      size_t base = ((size_t)n * CC + ccol) * SS + srow;
      floatx4 res = *(const floatx4*)&xin[base];
      floatx4 vo;
#pragma unroll
      for (int i = 0; i < 4; ++i) vo[i] = acc[mt][nt][i] + bov + res[i];
      *(floatx4*)&out[base] = vo;
    }
  }
}

// ---------------- host launcher ----------------
extern "C" void kernel_launch(void* const* d_in, const int* in_sizes, int n_in,
                              void* d_out, int out_size, void* d_ws, size_t ws_size,
                              hipStream_t stream) {
  const float* input   = (const float*)d_in[0];
  const float* context = (const float*)d_in[1];
  const float* gamma   = (const float*)d_in[2];
  const float* beta    = (const float*)d_in[3];
  const float* Wq      = (const float*)d_in[4];
  const float* bq      = (const float*)d_in[5];
  const float* Wkv     = (const float*)d_in[6];
  const float* bkv     = (const float*)d_in[7];
  const float* Wo      = (const float*)d_in[8];
  const float* bo      = (const float*)d_in[9];
  float* out = (float*)d_out;
  (void)in_sizes; (void)n_in; (void)out_size;

  char* ws = (char*)d_ws;
  size_t off = 0;
  auto alloc = [&](size_t b) {
    void* p = ws + off;
    off = (off + b + 255) & ~(size_t)255;
    return p;
  };
  // ---- common region (~32.3 MB) ----
  float*  part = (float*)alloc((size_t)4 * 128 * 2 * sizeof(float));
  float*  muA  = (float*)alloc(4 * sizeof(float));
  float*  rsA  = (float*)alloc(4 * sizeof(float));
  __bf16* WqB  = (__bf16*)alloc((size_t)4096 * 512 * 2);
  __bf16* WkvB = (__bf16*)alloc((size_t)8192 * 512 * 2);
  __bf16* WoB  = (__bf16*)alloc((size_t)512 * 4096 * 2);
  __bf16* xnT  = (__bf16*)alloc((size_t)NB * SS * CC * 2);
  __bf16* ctxT = (__bf16*)alloc((size_t)NB * SS * CC * 2);

  const size_t PB = (size_t)SS * 4096 * 2;  // 16 MB: one batch of q/k/v/y

  // ---- common prologue ----
  ln_partial<<<dim3(512), dim3(256), 0, stream>>>(input, part);
  ln_final<<<dim3(4), dim3(128), 0, stream>>>(part, muA, rsA);
  cast_w<<<dim3(2048), dim3(256), 0, stream>>>(Wq, WqB, 524288);
  cast_w<<<dim3(4096), dim3(256), 0, stream>>>(Wkv, WkvB, 1048576);
  cast_w<<<dim3(2048), dim3(256), 0, stream>>>(Wo, WoB, 524288);
  transpose_norm<<<dim3(64, 16, 4), dim3(32, 8), 0, stream>>>(input, xnT, muA, rsA, gamma, beta);
  transpose_norm<<<dim3(64, 16, 4), dim3(32, 8), 0, stream>>>(context, ctxT, nullptr, nullptr,
                                                              nullptr, nullptr);

  const size_t MiB = 1ull << 20;
  if (ws_size >= off + 16 * NB * PB / 4 + 8 * MiB) {
    // ---- Path A: full-batch buffers (needs ~288 MB + slack) ----
    __bf16* qTb = (__bf16*)alloc(NB * PB);
    __bf16* kTb = (__bf16*)alloc(NB * PB);
    __bf16* vB  = (__bf16*)alloc(NB * PB);
    __bf16* yTb = (__bf16*)alloc(NB * PB);
    gemm_q<<<dim3(32, 16, 4), dim3(256), 0, stream>>>(WqB, xnT, bq, qTb);
    gemm_kv<<<dim3(64, 16, 4), dim3(256), 0, stream>>>(WkvB, ctxT, bkv, kTb, vB);
    flash_attn<<<dim3(32, 8, 4), dim3(256), 0, stream>>>(qTb, kTb, vB, yTb);
    gemm_out<<<dim3(16, 4, 4), dim3(256), 0, stream>>>(yTb, WoB, bo, input, out);
  } else if (ws_size >= off + 7 * PB + 8 * MiB) {
    // ---- Path B: per-batch q/k/v (reused), full yT (~144 MB total) ----
    __bf16* qTb = (__bf16*)alloc(PB);
    __bf16* kTb = (__bf16*)alloc(PB);
    __bf16* vB  = (__bf16*)alloc(PB);
    __bf16* yTb = (__bf16*)alloc(NB * PB);
    for (int n = 0; n < NB; ++n) {
      gemm_q<<<dim3(32, 16, 1), dim3(256), 0, stream>>>(WqB, xnT + (size_t)n * SS * CC, bq, qTb);
      gemm_kv<<<dim3(64, 16, 1), dim3(256), 0, stream>>>(WkvB, ctxT + (size_t)n * SS * CC, bkv,
                                                         kTb, vB);
      flash_attn<<<dim3(32, 8, 1), dim3(256), 0, stream>>>(qTb, kTb, vB,
                                                           yTb + (size_t)n * SS * 4096);
    }
    gemm_out<<<dim3(16, 4, 4), dim3(256), 0, stream>>>(yTb, WoB, bo, input, out);
  } else {
    // ---- Path C: everything per-batch (~96 MB total) ----
    __bf16* qTb = (__bf16*)alloc(PB);
    __bf16* kTb = (__bf16*)alloc(PB);
    __bf16* vB  = (__bf16*)alloc(PB);
    __bf16* yTb = (__bf16*)alloc(PB);
    for (int n = 0; n < NB; ++n) {
      gemm_q<<<dim3(32, 16, 1), dim3(256), 0, stream>>>(WqB, xnT + (size_t)n * SS * CC, bq, qTb);
      gemm_kv<<<dim3(64, 16, 1), dim3(256), 0, stream>>>(WkvB, ctxT + (size_t)n * SS * CC, bkv,
                                                         kTb, vB);
      flash_attn<<<dim3(32, 8, 1), dim3(256), 0, stream>>>(qTb, kTb, vB, yTb);
      gemm_out<<<dim3(16, 4, 1), dim3(256), 0, stream>>>(yTb, WoB, bo,
                                                         input + (size_t)n * CC * SS,
                                                         out + (size_t)n * CC * SS);
    }
  }
}